// Round 1
// baseline (279.580 us; speedup 1.0000x reference)
//
#include <hip/hip_runtime.h>

// QuantLinearFP8: out[m,n] = sum_k x[m,k] * w[n,k] * scale[n, k/128] + bias[n]
// M=64, K=4096, N=11008, G=128.
//
// R4: barrier-free streaming pass1.
//  - xprep: convert x (1 MB, reused by all 1376 blocks) ONCE into bf16 MFMA
//    A-fragment layout xf[kb][t][lane] (512 KB, L2-resident). Each lane's
//    frag is one contiguous 16 B load -> no LDS, no cvt in the hot loop.
//  - pass1: zero LDS, zero __syncthreads. Pure stream: w float4 -> bf16
//    B-frag (compiler emits v_cvt_pk_bf16_f32), xf frag load (L2 hit), MFMA.
//    Waves fully independent -> deep outstanding-load pipelining.
//  - reduce: float4-vectorized split-K reduction + bias.
// ws layout: [0, 22.5MB) split-K partials f32; [22.5MB, +512KB) xf bf16.

#define Md 64
#define Kd 4096
#define Nd 11008
#define NGROUPS 32
#define BN 64
#define KSPLIT 8
#define KCHUNK (Kd / KSPLIT)     // 512
#define NGRP (KCHUNK / 128)      // 4 scale groups per chunk
#define KBC (KCHUNK / 32)        // 16 32-k steps per chunk

typedef __attribute__((ext_vector_type(8))) __bf16 bf16x8;
typedef __attribute__((ext_vector_type(4))) float f32x4;

// xf[kb][t][lane][j] = x[t*16 + (lane&15)][kb*32 + (lane>>4)*8 + j]
// (exactly the A-frag each lane feeds to mfma_f32_16x16x32_bf16)

__global__ __launch_bounds__(256)
void xprep(const float* __restrict__ x, __bf16* __restrict__ xf)
{
    const int tid  = blockIdx.x * 256 + threadIdx.x;  // frag id, 128*4*64 = 32768
    const int lane = tid & 63;
    const int t    = (tid >> 6) & 3;
    const int kb   = tid >> 8;
    const int row  = t * 16 + (lane & 15);
    const int col  = kb * 32 + (lane >> 4) * 8;
    const float4 a = *(const float4*)(x + (size_t)row * Kd + col);
    const float4 b = *(const float4*)(x + (size_t)row * Kd + col + 4);
    bf16x8 v = {(__bf16)a.x, (__bf16)a.y, (__bf16)a.z, (__bf16)a.w,
                (__bf16)b.x, (__bf16)b.y, (__bf16)b.z, (__bf16)b.w};
    *(bf16x8*)(xf + (size_t)tid * 8) = v;
}

__global__ __launch_bounds__(256, 4)
void qlinear_pass1(const float* __restrict__ w,
                   const __bf16* __restrict__ xf,
                   const float* __restrict__ scale,
                   float* __restrict__ ws)
{
    const int tid  = threadIdx.x;
    const int wv   = tid >> 6;         // wave -> n-substripe
    const int lane = tid & 63;
    const int quad = lane >> 4;
    const int ln   = lane & 15;

    const int n0 = blockIdx.x * BN;
    const int ky = blockIdx.y;
    const int k0 = ky * KCHUNK;

    // B-frag source: lane (quad,ln) holds w[nrow][k0 + kb*32 + quad*8 + j]
    const int nrow = n0 + wv * 16 + ln;
    const float* wp = w + (size_t)nrow * Kd + k0 + quad * 8;

    // A-frag source: pre-converted bf16 frags, 16 B per lane per (kb,t)
    const __bf16* xp = xf + (size_t)ky * KBC * 4 * 512 + lane * 8;

    // 4 group scales for this chunk (contiguous 16 B)
    float4 sc4 = *(const float4*)(scale + (size_t)nrow * NGROUPS + ky * NGRP);
    const float sc[4] = {sc4.x, sc4.y, sc4.z, sc4.w};

    f32x4 acc[4];
    #pragma unroll
    for (int t = 0; t < 4; ++t) acc[t] = (f32x4){0.f, 0.f, 0.f, 0.f};

    #pragma unroll
    for (int g = 0; g < NGRP; ++g) {
        f32x4 pg[4];
        #pragma unroll
        for (int t = 0; t < 4; ++t) pg[t] = (f32x4){0.f, 0.f, 0.f, 0.f};

        #pragma unroll
        for (int s = 0; s < 4; ++s) {
            const int kb = g * 4 + s;               // 32-k step in chunk
            float4 wa = *(const float4*)(wp + kb * 32);
            float4 wb = *(const float4*)(wp + kb * 32 + 4);
            bf16x8 wf = {(__bf16)wa.x, (__bf16)wa.y, (__bf16)wa.z, (__bf16)wa.w,
                         (__bf16)wb.x, (__bf16)wb.y, (__bf16)wb.z, (__bf16)wb.w};
            #pragma unroll
            for (int t = 0; t < 4; ++t) {
                bf16x8 xv = *(const bf16x8*)(xp + ((size_t)kb * 4 + t) * 512);
                pg[t] = __builtin_amdgcn_mfma_f32_16x16x32_bf16(xv, wf, pg[t],
                                                                0, 0, 0);
            }
        }

        const float s = sc[g];
        #pragma unroll
        for (int t = 0; t < 4; ++t)
            #pragma unroll
            for (int r = 0; r < 4; ++r)
                acc[t][r] += s * pg[t][r];
    }

    // partials -> ws[ky][m][n]  (C/D: m = t*16 + quad*4 + r, col = ln)
    float* op = ws + ((size_t)ky * Md) * Nd + n0 + wv * 16 + ln;
    #pragma unroll
    for (int t = 0; t < 4; ++t)
        #pragma unroll
        for (int r = 0; r < 4; ++r)
            op[(size_t)(t * 16 + quad * 4 + r) * Nd] = acc[t][r];
}

__global__ __launch_bounds__(256)
void qlinear_reduce(const float* __restrict__ ws,
                    const float* __restrict__ bias,
                    float* __restrict__ out)
{
    const int i4 = blockIdx.x * 256 + threadIdx.x;   // float4 index
    if (i4 >= (Md * Nd) / 4) return;
    const int n = (i4 * 4) % Nd;                     // Nd % 4 == 0
    float4 v = *(const float4*)(bias + n);
    #pragma unroll
    for (int ky = 0; ky < KSPLIT; ++ky) {
        float4 p = *(const float4*)(ws + (size_t)ky * Md * Nd + (size_t)i4 * 4);
        v.x += p.x; v.y += p.y; v.z += p.z; v.w += p.w;
    }
    *(float4*)(out + (size_t)i4 * 4) = v;
}

extern "C" void kernel_launch(void* const* d_in, const int* in_sizes, int n_in,
                              void* d_out, int out_size, void* d_ws, size_t ws_size,
                              hipStream_t stream) {
    const float* x     = (const float*)d_in[0];  // [64][4096]
    const float* w     = (const float*)d_in[1];  // [11008][4096]
    const float* scale = (const float*)d_in[2];  // [11008][32]
    const float* bias  = (const float*)d_in[3];  // [11008]
    float* out = (float*)d_out;                  // [64][11008] f32
    float* ws  = (float*)d_ws;                   // partials 22.5 MB + xf 512 KB

    __bf16* xf = (__bf16*)(ws + (size_t)KSPLIT * Md * Nd);  // 16B-aligned

    xprep<<<128, 256, 0, stream>>>(x, xf);

    dim3 grid1(Nd / BN, KSPLIT);
    qlinear_pass1<<<grid1, 256, 0, stream>>>(w, xf, scale, ws);

    qlinear_reduce<<<(Md * Nd / 4 + 255) / 256, 256, 0, stream>>>(ws, bias, out);
}

// Round 2
// 273.826 us; speedup vs baseline: 1.0210x; 1.0210x over previous
//
#include <hip/hip_runtime.h>

// QuantLinearFP8: out[m,n] = sum_k x[m,k] * w[n,k] * scale[n, k/128] + bias[n]
// M=64, K=4096, N=11008, G=128.
//
// R5: coalesced w streaming via global_load_lds (width=16), double-buffered
// LDS, 2-phase schedule (T3-min). Rationale: R3/R4's direct w gather
// (16 rows x 16KB stride per wave-load) is the suspected BW limiter; this
// converts it to 4x contiguous 256B runs per staging issue.
//  - LDS tile [64 rows][64 f32], linear dest; bank-conflict-free frag reads
//    via XOR-swizzled SOURCE chunks (c16 ^= row&7) + same XOR on ds_read
//    (rule 21: linear dest + inv-swz source + swz read).
//  - x: pre-converted bf16 A-frags (xprep), L2-resident, loaded per-MFMA.
//  - 1 __syncthreads per BK=64 stage; STAGE(s+1) issued before compute(s).
// ws layout: [0, 22.5MB) split-K partials f32; [22.5MB, +512KB) xf bf16.

#define Md 64
#define Kd 4096
#define Nd 11008
#define NGROUPS 32
#define BN 64
#define KSPLIT 8
#define KCHUNK (Kd / KSPLIT)     // 512
#define NSTAGE (KCHUNK / 64)     // 8 BK=64 stages per chunk
#define NGRP (KCHUNK / 128)      // 4 scale groups per chunk
#define KBC (KCHUNK / 32)        // 16 32-k steps per chunk

typedef __attribute__((ext_vector_type(8))) __bf16 bf16x8;
typedef __attribute__((ext_vector_type(4))) float f32x4;

// xf[kb][t][lane][j] = x[t*16 + (lane&15)][kb*32 + (lane>>4)*8 + j]
__global__ __launch_bounds__(256)
void xprep(const float* __restrict__ x, __bf16* __restrict__ xf)
{
    const int tid  = blockIdx.x * 256 + threadIdx.x;  // frag id, 128*4*64 = 32768
    const int lane = tid & 63;
    const int t    = (tid >> 6) & 3;
    const int kb   = tid >> 8;
    const int row  = t * 16 + (lane & 15);
    const int col  = kb * 32 + (lane >> 4) * 8;
    const float4 a = *(const float4*)(x + (size_t)row * Kd + col);
    const float4 b = *(const float4*)(x + (size_t)row * Kd + col + 4);
    bf16x8 v = {(__bf16)a.x, (__bf16)a.y, (__bf16)a.z, (__bf16)a.w,
                (__bf16)b.x, (__bf16)b.y, (__bf16)b.z, (__bf16)b.w};
    *(bf16x8*)(xf + (size_t)tid * 8) = v;
}

__global__ __launch_bounds__(256, 4)
void qlinear_pass1(const float* __restrict__ w,
                   const __bf16* __restrict__ xf,
                   const float* __restrict__ scale,
                   float* __restrict__ ws)
{
    const int tid  = threadIdx.x;
    const int wv   = tid >> 6;         // wave -> n-substripe
    const int lane = tid & 63;
    const int quad = lane >> 4;
    const int ln   = lane & 15;

    const int n0 = blockIdx.x * BN;
    const int ky = blockIdx.y;
    const int k0 = ky * KCHUNK;

    __shared__ alignas(16) float lds_w[2][BN * 64];   // 2 x 16 KB

    // Staging: issue j covers rows wv*16+j*4 .. +3 (4 x 256B contiguous runs).
    // Source chunk is XOR-swizzled so linear LDS holds swizzled layout.
    const float* src[4];
    #pragma unroll
    for (int j = 0; j < 4; ++j) {
        const int r   = wv * 16 + j * 4 + quad;   // row this lane feeds
        const int c16 = ln ^ (r & 7);             // swizzled 16B-chunk in row
        src[j] = w + (size_t)(n0 + r) * Kd + k0 + c16 * 4;
    }

    // A-frag source: pre-converted bf16 frags, 16 B per lane per (kb,t)
    const __bf16* xp = xf + (size_t)ky * KBC * 4 * 512 + (size_t)lane * 8;

    const int nrow = n0 + wv * 16 + ln;
    float4 sc4 = *(const float4*)(scale + (size_t)nrow * NGROUPS + ky * NGRP);
    const float sc[4] = {sc4.x, sc4.y, sc4.z, sc4.w};

    // frag-read row + swizzle key
    const int rr = wv * 16 + ln;
    const int rx = rr & 7;

    f32x4 acc[4];
    #pragma unroll
    for (int t = 0; t < 4; ++t) acc[t] = (f32x4){0.f, 0.f, 0.f, 0.f};

    // prologue: stage 0 into buf 0
    #pragma unroll
    for (int j = 0; j < 4; ++j)
        __builtin_amdgcn_global_load_lds(
            (const __attribute__((address_space(1))) void*)src[j],
            (__attribute__((address_space(3))) void*)&lds_w[0][(wv * 4 + j) * 256],
            16, 0, 0);
    __syncthreads();

    #pragma unroll
    for (int g = 0; g < NGRP; ++g) {
        f32x4 pg[4];
        #pragma unroll
        for (int t = 0; t < 4; ++t) pg[t] = (f32x4){0.f, 0.f, 0.f, 0.f};

        #pragma unroll
        for (int half = 0; half < 2; ++half) {
            const int s   = g * 2 + half;
            const int buf = s & 1;

            // prefetch next stage into the other buffer (before compute)
            if (s + 1 < NSTAGE) {
                #pragma unroll
                for (int j = 0; j < 4; ++j)
                    __builtin_amdgcn_global_load_lds(
                        (const __attribute__((address_space(1))) void*)(src[j] + (s + 1) * 64),
                        (__attribute__((address_space(3))) void*)&lds_w[buf ^ 1][(wv * 4 + j) * 256],
                        16, 0, 0);
            }

            // compute stage s: 2 k-steps of 32
            #pragma unroll
            for (int ks = 0; ks < 2; ++ks) {
                const int kb = s * 2 + ks;
                bf16x8 xv[4];
                #pragma unroll
                for (int t = 0; t < 4; ++t)
                    xv[t] = *(const bf16x8*)(xp + ((size_t)kb * 4 + t) * 512);

                const int c0 = ks * 8 + quad * 2;
                f32x4 fa = *(const f32x4*)&lds_w[buf][rr * 64 + (((c0    ) ^ rx) << 2)];
                f32x4 fb = *(const f32x4*)&lds_w[buf][rr * 64 + (((c0 + 1) ^ rx) << 2)];
                bf16x8 wf = {(__bf16)fa.x, (__bf16)fa.y, (__bf16)fa.z, (__bf16)fa.w,
                             (__bf16)fb.x, (__bf16)fb.y, (__bf16)fb.z, (__bf16)fb.w};
                #pragma unroll
                for (int t = 0; t < 4; ++t)
                    pg[t] = __builtin_amdgcn_mfma_f32_16x16x32_bf16(xv[t], wf, pg[t],
                                                                    0, 0, 0);
            }
            __syncthreads();   // drains staging loads; buf[s&1] now reusable
        }

        const float s = sc[g];
        #pragma unroll
        for (int t = 0; t < 4; ++t)
            #pragma unroll
            for (int r = 0; r < 4; ++r)
                acc[t][r] += s * pg[t][r];
    }

    // partials -> ws[ky][m][n]  (C/D: m = t*16 + quad*4 + r, col = ln)
    float* op = ws + ((size_t)ky * Md) * Nd + n0 + wv * 16 + ln;
    #pragma unroll
    for (int t = 0; t < 4; ++t)
        #pragma unroll
        for (int r = 0; r < 4; ++r)
            op[(size_t)(t * 16 + quad * 4 + r) * Nd] = acc[t][r];
}

__global__ __launch_bounds__(256)
void qlinear_reduce(const float* __restrict__ ws,
                    const float* __restrict__ bias,
                    float* __restrict__ out)
{
    const int i4 = blockIdx.x * 256 + threadIdx.x;   // float4 index
    if (i4 >= (Md * Nd) / 4) return;
    const int n = (i4 * 4) % Nd;                     // Nd % 4 == 0
    float4 v = *(const float4*)(bias + n);
    #pragma unroll
    for (int ky = 0; ky < KSPLIT; ++ky) {
        float4 p = *(const float4*)(ws + (size_t)ky * Md * Nd + (size_t)i4 * 4);
        v.x += p.x; v.y += p.y; v.z += p.z; v.w += p.w;
    }
    *(float4*)(out + (size_t)i4 * 4) = v;
}

extern "C" void kernel_launch(void* const* d_in, const int* in_sizes, int n_in,
                              void* d_out, int out_size, void* d_ws, size_t ws_size,
                              hipStream_t stream) {
    const float* x     = (const float*)d_in[0];  // [64][4096]
    const float* w     = (const float*)d_in[1];  // [11008][4096]
    const float* scale = (const float*)d_in[2];  // [11008][32]
    const float* bias  = (const float*)d_in[3];  // [11008]
    float* out = (float*)d_out;                  // [64][11008] f32
    float* ws  = (float*)d_ws;                   // partials 22.5 MB + xf 512 KB

    __bf16* xf = (__bf16*)(ws + (size_t)KSPLIT * Md * Nd);  // 16B-aligned

    xprep<<<128, 256, 0, stream>>>(x, xf);

    dim3 grid1(Nd / BN, KSPLIT);
    qlinear_pass1<<<grid1, 256, 0, stream>>>(w, xf, scale, ws);

    qlinear_reduce<<<(Md * Nd / 4 + 255) / 256, 256, 0, stream>>>(ws, bias, out);
}

// Round 3
// 269.174 us; speedup vs baseline: 1.0387x; 1.0173x over previous
//
#include <hip/hip_runtime.h>

// QuantLinearFP8: out[m,n] = sum_k x[m,k] * w[n,k] * scale[n, k/128] + bias[n]
// M=64, K=4096, N=11008, G=128.
//
// R6: delete the reduce pass. Split-K partials now go straight into out via
// hardware f32 atomics (unsafeAtomicAdd -> global_atomic_add_f32; 8 writers
// per address, spread in time). out is pre-initialized to bias by `prep`,
// which also does the xprep conversion (fused -> one launch).
// Saves: reduce kernel (~8 us + launch gap) and the 45 MB ws round-trip.
// pass1 body is identical to R5 (best measured): global_load_lds width=16,
// double-buffered LDS, XOR-swizzled source chunks + swizzled ds_read.
// ws layout: only xf bf16 (512 KB) at offset 0.

#define Md 64
#define Kd 4096
#define Nd 11008
#define NGROUPS 32
#define BN 64
#define KSPLIT 8
#define KCHUNK (Kd / KSPLIT)     // 512
#define NSTAGE (KCHUNK / 64)     // 8 BK=64 stages per chunk
#define NGRP (KCHUNK / 128)      // 4 scale groups per chunk
#define KBC (KCHUNK / 32)        // 16 32-k steps per chunk

typedef __attribute__((ext_vector_type(8))) __bf16 bf16x8;
typedef __attribute__((ext_vector_type(4))) float f32x4;

// blocks [0,128):   xf[kb][t][lane][j] = x[t*16+(lane&15)][kb*32+(lane>>4)*8+j]
// blocks [128,816): out[i] = bias[i % Nd]  (bias pre-init for atomic split-K)
__global__ __launch_bounds__(256)
void prep(const float* __restrict__ x, __bf16* __restrict__ xf,
          const float* __restrict__ bias, float* __restrict__ out)
{
    if (blockIdx.x < 128) {
        const int tid  = blockIdx.x * 256 + threadIdx.x;  // frag id, 32768
        const int lane = tid & 63;
        const int t    = (tid >> 6) & 3;
        const int kb   = tid >> 8;
        const int row  = t * 16 + (lane & 15);
        const int col  = kb * 32 + (lane >> 4) * 8;
        const float4 a = *(const float4*)(x + (size_t)row * Kd + col);
        const float4 b = *(const float4*)(x + (size_t)row * Kd + col + 4);
        bf16x8 v = {(__bf16)a.x, (__bf16)a.y, (__bf16)a.z, (__bf16)a.w,
                    (__bf16)b.x, (__bf16)b.y, (__bf16)b.z, (__bf16)b.w};
        *(bf16x8*)(xf + (size_t)tid * 8) = v;
    } else {
        const int i4 = (blockIdx.x - 128) * 256 + threadIdx.x; // 176128 = Md*Nd/4
        const int n  = (i4 * 4) % Nd;                          // Nd % 4 == 0
        *(float4*)(out + (size_t)i4 * 4) = *(const float4*)(bias + n);
    }
}

__global__ __launch_bounds__(256, 4)
void qlinear_pass1(const float* __restrict__ w,
                   const __bf16* __restrict__ xf,
                   const float* __restrict__ scale,
                   float* __restrict__ out)
{
    const int tid  = threadIdx.x;
    const int wv   = tid >> 6;         // wave -> n-substripe
    const int lane = tid & 63;
    const int quad = lane >> 4;
    const int ln   = lane & 15;

    const int n0 = blockIdx.x * BN;
    const int ky = blockIdx.y;
    const int k0 = ky * KCHUNK;

    __shared__ alignas(16) float lds_w[2][BN * 64];   // 2 x 16 KB

    // Staging: issue j covers rows wv*16+j*4 .. +3 (4 x 256B contiguous runs).
    // Source chunk is XOR-swizzled so linear LDS holds swizzled layout.
    const float* src[4];
    #pragma unroll
    for (int j = 0; j < 4; ++j) {
        const int r   = wv * 16 + j * 4 + quad;   // row this lane feeds
        const int c16 = ln ^ (r & 7);             // swizzled 16B-chunk in row
        src[j] = w + (size_t)(n0 + r) * Kd + k0 + c16 * 4;
    }

    // A-frag source: pre-converted bf16 frags, 16 B per lane per (kb,t)
    const __bf16* xp = xf + (size_t)ky * KBC * 4 * 512 + (size_t)lane * 8;

    const int nrow = n0 + wv * 16 + ln;
    float4 sc4 = *(const float4*)(scale + (size_t)nrow * NGROUPS + ky * NGRP);
    const float sc[4] = {sc4.x, sc4.y, sc4.z, sc4.w};

    // frag-read row + swizzle key
    const int rr = wv * 16 + ln;
    const int rx = rr & 7;

    f32x4 acc[4];
    #pragma unroll
    for (int t = 0; t < 4; ++t) acc[t] = (f32x4){0.f, 0.f, 0.f, 0.f};

    // prologue: stage 0 into buf 0
    #pragma unroll
    for (int j = 0; j < 4; ++j)
        __builtin_amdgcn_global_load_lds(
            (const __attribute__((address_space(1))) void*)src[j],
            (__attribute__((address_space(3))) void*)&lds_w[0][(wv * 4 + j) * 256],
            16, 0, 0);
    __syncthreads();

    #pragma unroll
    for (int g = 0; g < NGRP; ++g) {
        f32x4 pg[4];
        #pragma unroll
        for (int t = 0; t < 4; ++t) pg[t] = (f32x4){0.f, 0.f, 0.f, 0.f};

        #pragma unroll
        for (int half = 0; half < 2; ++half) {
            const int s   = g * 2 + half;
            const int buf = s & 1;

            // prefetch next stage into the other buffer (before compute)
            if (s + 1 < NSTAGE) {
                #pragma unroll
                for (int j = 0; j < 4; ++j)
                    __builtin_amdgcn_global_load_lds(
                        (const __attribute__((address_space(1))) void*)(src[j] + (s + 1) * 64),
                        (__attribute__((address_space(3))) void*)&lds_w[buf ^ 1][(wv * 4 + j) * 256],
                        16, 0, 0);
            }

            // compute stage s: 2 k-steps of 32
            #pragma unroll
            for (int ks = 0; ks < 2; ++ks) {
                const int kb = s * 2 + ks;
                bf16x8 xv[4];
                #pragma unroll
                for (int t = 0; t < 4; ++t)
                    xv[t] = *(const bf16x8*)(xp + ((size_t)kb * 4 + t) * 512);

                const int c0 = ks * 8 + quad * 2;
                f32x4 fa = *(const f32x4*)&lds_w[buf][rr * 64 + (((c0    ) ^ rx) << 2)];
                f32x4 fb = *(const f32x4*)&lds_w[buf][rr * 64 + (((c0 + 1) ^ rx) << 2)];
                bf16x8 wf = {(__bf16)fa.x, (__bf16)fa.y, (__bf16)fa.z, (__bf16)fa.w,
                             (__bf16)fb.x, (__bf16)fb.y, (__bf16)fb.z, (__bf16)fb.w};
                #pragma unroll
                for (int t = 0; t < 4; ++t)
                    pg[t] = __builtin_amdgcn_mfma_f32_16x16x32_bf16(xv[t], wf, pg[t],
                                                                    0, 0, 0);
            }
            __syncthreads();   // drains staging loads; buf[s&1] now reusable
        }

        const float s = sc[g];
        #pragma unroll
        for (int t = 0; t < 4; ++t)
            #pragma unroll
            for (int r = 0; r < 4; ++r)
                acc[t][r] += s * pg[t][r];
    }

    // atomic split-K epilogue -> out[m][n]  (C/D: m = t*16+quad*4+r, col = ln)
    float* op = out + n0 + wv * 16 + ln;
    #pragma unroll
    for (int t = 0; t < 4; ++t)
        #pragma unroll
        for (int r = 0; r < 4; ++r)
            unsafeAtomicAdd(&op[(size_t)(t * 16 + quad * 4 + r) * Nd], acc[t][r]);
}

extern "C" void kernel_launch(void* const* d_in, const int* in_sizes, int n_in,
                              void* d_out, int out_size, void* d_ws, size_t ws_size,
                              hipStream_t stream) {
    const float* x     = (const float*)d_in[0];  // [64][4096]
    const float* w     = (const float*)d_in[1];  // [11008][4096]
    const float* scale = (const float*)d_in[2];  // [11008][32]
    const float* bias  = (const float*)d_in[3];  // [11008]
    float* out = (float*)d_out;                  // [64][11008] f32
    float* ws  = (float*)d_ws;                   // xf bf16 (512 KB)

    __bf16* xf = (__bf16*)ws;                    // 16B-aligned

    prep<<<816, 256, 0, stream>>>(x, xf, bias, out);

    dim3 grid1(Nd / BN, KSPLIT);
    qlinear_pass1<<<grid1, 256, 0, stream>>>(w, xf, scale, out);
}